// Round 8
// baseline (352.792 us; speedup 1.0000x reference)
//
#include <hip/hip_runtime.h>
#include <math.h>

#define SEQ 2048
#define HID_DIM 2048
#define NH 16
#define NKV 4
#define HD 128
#define QS 3072   // fused qkv row stride (bf16): [q 2048 | k 512 | v 512]

typedef float  f4v  __attribute__((ext_vector_type(4)));
typedef __bf16 bf8v __attribute__((ext_vector_type(8)));
typedef __bf16 bf4v __attribute__((ext_vector_type(4)));
typedef __bf16 bf2v __attribute__((ext_vector_type(2)));

typedef __attribute__((address_space(1))) const void* gvp;
typedef __attribute__((address_space(3))) void*       svp;

__device__ __forceinline__ void gld16(const void* g, void* lds_wave_base) {
    __builtin_amdgcn_global_load_lds((gvp)g, (svp)lds_wave_base, 16, 0, 0);
}

__device__ __forceinline__ void wgb() {
    asm volatile("" ::: "memory");
    __builtin_amdgcn_s_barrier();
    asm volatile("" ::: "memory");
}
#define VMC(n) asm volatile("s_waitcnt vmcnt(" #n ")" ::: "memory")

// ---- single fused fp32 -> bf16 convert pass ----------------------------
__global__ __launch_bounds__(256)
void cvt_all(__bf16* __restrict__ Acat, __bf16* __restrict__ Wcat,
             __bf16* __restrict__ Wo,
             const float* __restrict__ hs, const float* __restrict__ mu,
             const float* __restrict__ wq, const float* __restrict__ wmq,
             const float* __restrict__ wk, const float* __restrict__ wmk,
             const float* __restrict__ wv, const float* __restrict__ wmv,
             const float* __restrict__ wo)
{
    int b = blockIdx.x;
    const float *s0, *s1; __bf16* dst;
    if (b < 8192)       { s0 = hs; s1 = mu;  dst = Acat; }
    else if (b < 16384) { s0 = wq; s1 = wmq; dst = Wcat;                            b -= 8192; }
    else if (b < 18432) { s0 = wk; s1 = wmk; dst = Wcat + (size_t)2048 * 4096;      b -= 16384; }
    else if (b < 20480) { s0 = wv; s1 = wmv; dst = Wcat + (size_t)2560 * 4096;      b -= 18432; }
    else {
        int i = (b - 20480) * 256 + threadIdx.x;
        float4 v = *reinterpret_cast<const float4*>(wo + (size_t)i * 4);
        *reinterpret_cast<bf4v*>(Wo + (size_t)i * 4) =
            bf4v{ (__bf16)v.x, (__bf16)v.y, (__bf16)v.z, (__bf16)v.w };
        return;
    }
    int i = b * 256 + threadIdx.x;
    int row = i >> 10, c = i & 1023;               // 1024 quads per dst row
    const float* s = (c < 512) ? s0 + ((size_t)row * 512 + c) * 4
                               : s1 + ((size_t)row * 512 + (c - 512)) * 4;
    float4 v = *reinterpret_cast<const float4*>(s);
    *reinterpret_cast<bf4v*>(dst + ((size_t)row * 1024 + c) * 4) =
        bf4v{ (__bf16)v.x, (__bf16)v.y, (__bf16)v.z, (__bf16)v.w };
}

// ---- 256x256 pipelined split-K NT GEMM ---------------------------------
// R5-verified schedule. NEW (R7): XCD-chunked blockIdx swizzle (T1,
// bijective since nwg%8==0) + mode-1 epilogue: fp32 atomicAdd into OutF
// (out zeroed by memsetAsync; each address hit by exactly gridDim.z blocks).
__device__ __forceinline__ void stage_half(
    const __bf16* __restrict__ g, int ldk, int row0, int ktile, int half,
    char* buf, int w, int sr, int sc)
{
#pragma unroll
    for (int j = 0; j < 2; ++j) {
        int sid = w * 2 + j;                       // 16 subtiles / half-tile
        int rb = half * 8 + (sid >> 1), cb = sid & 1;
        gld16(g + (size_t)(row0 + rb * 16 + sr) * ldk + ktile * 64 + cb * 32 + sc,
              buf + (rb * 2 + cb) * 1024);
    }
}
__device__ __forceinline__ void stage_tile(
    const __bf16* __restrict__ g, int ldk, int row0, int ktile,
    char* buf, int w, int sr, int sc)
{
    stage_half(g, ldk, row0, ktile, 0, buf, w, sr, sc);
    stage_half(g, ldk, row0, ktile, 1, buf, w, sr, sc);
}

#define LOAD_AF(DST, BUF, MTB) \
    _Pragma("unroll") for (int mt = 0; mt < 4; ++mt) \
    _Pragma("unroll") for (int ks = 0; ks < 2; ++ks) \
        DST[mt][ks] = *(const bf8v*)((BUF) + (((wm * 8 + (MTB) + mt) * 2 + ks) << 10) + frag_off);
#define LOAD_BF(DST, BUF, NTB) \
    _Pragma("unroll") for (int nt = 0; nt < 2; ++nt) \
    _Pragma("unroll") for (int ks = 0; ks < 2; ++ks) \
        DST[nt][ks] = *(const bf8v*)((BUF) + (((wn * 4 + (NTB) + nt) * 2 + ks) << 10) + frag_off);
#define MFMA_Q(MTB, NTB, AR, BR) \
    __builtin_amdgcn_s_setprio(1); \
    _Pragma("unroll") for (int mt = 0; mt < 4; ++mt) \
    _Pragma("unroll") for (int nt = 0; nt < 2; ++nt) \
    _Pragma("unroll") for (int ks = 0; ks < 2; ++ks) \
        acc[(MTB) + mt][(NTB) + nt] = __builtin_amdgcn_mfma_f32_16x16x32_bf16( \
            AR[mt][ks], BR[nt][ks], acc[(MTB) + mt][(NTB) + nt], 0, 0, 0); \
    __builtin_amdgcn_s_setprio(0);

__global__ __launch_bounds__(512, 2)
void gemm_nt_pl(const __bf16* __restrict__ A, const __bf16* __restrict__ B,
                __bf16* __restrict__ P, int M, int N, int K, int KS,
                float* __restrict__ OutF, int mode)
{
    __shared__ __align__(1024) char lds[131072];
    char* A0 = lds;
    char* A1 = lds + 32768;
    char* B0 = lds + 65536;
    char* B1 = lds + 98304;

    const int tid = threadIdx.x, lane = tid & 63, w = tid >> 6;
    const int wm = w >> 2, wn = w & 3;
    const int mm = lane & 15, quad = lane >> 4;

    // XCD-chunked swizzle (nwg % 8 == 0 for all launches here)
    const int nbx = gridDim.x, nby = gridDim.y;
    int flat = blockIdx.x + nbx * (blockIdx.y + nby * blockIdx.z);
    const int cpx = (nbx * nby * gridDim.z) >> 3;
    flat = (flat & 7) * cpx + (flat >> 3);
    const int bxi = flat % nbx, byi = (flat / nbx) % nby, bzi = flat / (nbx * nby);

    const int m0 = byi * 256, n0 = bxi * 256;
    const int kt0 = (bzi * KS) >> 6;
    const int T = KS >> 6;                          // K-tiles per block (>=4, even)

    const int sr = lane >> 2, sc = (lane & 3) * 8;  // staging lane offsets
    const int frag_off = (mm * 4 + quad) << 4;      // frag read offset in subtile

    f4v acc[8][4] = {};
    bf8v aLo[4][2], aHi[4][2], b01e[2][2], b01o[2][2], b23[2][2];

    // prologue: fully stage tiles kt0 (buf0), kt0+1 (buf1)
    stage_tile(A, K, m0, kt0,     A0, w, sr, sc);
    stage_tile(B, K, n0, kt0,     B0, w, sr, sc);
    stage_tile(A, K, m0, kt0 + 1, A1, w, sr, sc);
    stage_tile(B, K, n0, kt0 + 1, B1, w, sr, sc);
    VMC(8);                                         // drain tile kt0 (oldest 8)
    wgb();
    LOAD_AF(aLo, A0, 0)
    LOAD_BF(b01e, B0, 0)

    const int nbody = (T - 2) >> 1;
    for (int it = 0; it < nbody; ++it) {
        const int t2 = kt0 + 2 * it + 2, t3 = t2 + 1;
        // P1: rd b23(t); MFMA Q1(t)
        LOAD_BF(b23, B0, 2)
        MFMA_Q(0, 0, aLo, b01e)
        wgb();
        // P2: rd aHi(t); MFMA Q2(t); drain t+1
        LOAD_AF(aHi, A0, 4)
        MFMA_Q(0, 2, aLo, b23)
        VMC(0);
        wgb();
        // P3: rd aLo(t+1); stage B(t+2)->B0; MFMA Q3(t)
        LOAD_AF(aLo, A1, 0)
        stage_tile(B, K, n0, t2, B0, w, sr, sc);
        MFMA_Q(4, 2, aHi, b23)
        wgb();
        // P4: rd b01(t+1); stage A(t+2)->A0; MFMA Q4(t)
        LOAD_BF(b01o, B1, 0)
        stage_tile(A, K, m0, t2, A0, w, sr, sc);
        MFMA_Q(4, 0, aHi, b01e)
        wgb();
        // P5: rd b23(t+1); MFMA Q1(t+1)
        LOAD_BF(b23, B1, 2)
        MFMA_Q(0, 0, aLo, b01o)
        wgb();
        // P6: rd aHi(t+1); MFMA Q2(t+1); drain t+2
        LOAD_AF(aHi, A1, 4)
        MFMA_Q(0, 2, aLo, b23)
        VMC(0);
        wgb();
        // P7: rd aLo(t+2); stage B(t+3)->B1; MFMA Q3(t+1)
        LOAD_AF(aLo, A0, 0)
        stage_tile(B, K, n0, t3, B1, w, sr, sc);
        MFMA_Q(4, 2, aHi, b23)
        wgb();
        // P8: rd b01(t+2); stage A(t+3)->A1; MFMA Q4(t+1)
        LOAD_BF(b01e, B0, 0)
        stage_tile(A, K, m0, t3, A1, w, sr, sc);
        MFMA_Q(4, 0, aHi, b01o)
        wgb();
    }
    // tail: tiles T-2 (buf0), T-1 (buf1); no staging
    LOAD_BF(b23, B0, 2)
    MFMA_Q(0, 0, aLo, b01e)
    wgb();
    LOAD_AF(aHi, A0, 4)
    MFMA_Q(0, 2, aLo, b23)
    VMC(0);
    wgb();
    LOAD_AF(aLo, A1, 0)
    MFMA_Q(4, 2, aHi, b23)
    wgb();
    LOAD_BF(b01o, B1, 0)
    MFMA_Q(4, 0, aHi, b01e)
    wgb();
    LOAD_BF(b23, B1, 2)
    MFMA_Q(0, 0, aLo, b01o)
    wgb();
    LOAD_AF(aHi, A1, 4)
    MFMA_Q(0, 2, aLo, b23)
    wgb();
    MFMA_Q(4, 2, aHi, b23)
    MFMA_Q(4, 0, aHi, b01o)

    if (mode) {
        // split-K accumulate straight into fp32 output (zeroed beforehand)
#pragma unroll
        for (int mt = 0; mt < 8; ++mt)
#pragma unroll
            for (int nt = 0; nt < 4; ++nt)
#pragma unroll
                for (int r = 0; r < 4; ++r)
                    atomicAdd(&OutF[(size_t)(m0 + wm * 128 + mt * 16 + quad * 4 + r) * N
                                    + n0 + wn * 64 + nt * 16 + mm], acc[mt][nt][r]);
    } else {
        __bf16* Pz = P + (size_t)bzi * M * N;
#pragma unroll
        for (int mt = 0; mt < 8; ++mt)
#pragma unroll
            for (int nt = 0; nt < 4; ++nt)
#pragma unroll
                for (int r = 0; r < 4; ++r)
                    Pz[(size_t)(m0 + wm * 128 + mt * 16 + quad * 4 + r) * N
                       + n0 + wn * 64 + nt * 16 + mm] = (__bf16)acc[mt][nt][r];
    }
}

// ---- norm_rope fused with K-pack AND V-pack ----------------------------
// q-heads (hh<16): RMSNorm+RoPE in place. k-heads (16..19): normed+roped
// rows written straight into the packed XOR-swizzled Kt image. v-heads
// (20..23): partial-sum only, written transposed into the Vt image
// (elem d of row s -> byte d*128 + ((kc^(d&7))<<4) + j*2, kc=(s>>3)&7,
// j=s&7 — matches attn's V-read). Block = (64,4), grid y = 6.
__global__ __launch_bounds__(256)
void norm_rope_pk(__bf16* __restrict__ qkv /* p0, q in place */,
                  const __bf16* __restrict__ p1,
                  const float* __restrict__ qw, const float* __restrict__ kw,
                  __bf16* __restrict__ Kt, __bf16* __restrict__ Vt)
{
    const int s = blockIdx.x, hh = blockIdx.y * 4 + threadIdx.y, l = threadIdx.x;
    if (hh >= NH + NKV) {                          // ---- V path ----
        const int vh = hh - (NH + NKV);
        const int off = 2560 + vh * HD;
        const __bf16* p  = qkv + (size_t)s * QS + off;
        const __bf16* q1 = p1  + (size_t)s * QS + off;
        float x0 = (float)p[l]      + (float)q1[l];
        float x1 = (float)p[l + 64] + (float)q1[l + 64];
        char* tile = (char*)Vt + (size_t)(vh * 32 + (s >> 6)) * 16384;
        const int kc = (s >> 3) & 7, j = s & 7;
        const int d2 = l + 64;
        *reinterpret_cast<__bf16*>(tile + l  * 128 + ((kc ^ (l  & 7)) << 4) + j * 2) = (__bf16)x0;
        *reinterpret_cast<__bf16*>(tile + d2 * 128 + ((kc ^ (d2 & 7)) << 4) + j * 2) = (__bf16)x1;
        return;
    }
    const float* wn; float scale; int off;
    if (hh < NH) { off = hh * HD;               wn = qw; scale = 0.08838834764831845f; }
    else         { off = 2048 + (hh - NH) * HD; wn = kw; scale = 1.0f; }
    __bf16* p = qkv + (size_t)s * QS + off;
    const __bf16* q1 = p1 + (size_t)s * QS + off;
    float x0 = (float)p[l]      + (float)q1[l];
    float x1 = (float)p[l + 64] + (float)q1[l + 64];
    float ss = x0 * x0 + x1 * x1;
#pragma unroll
    for (int o = 32; o; o >>= 1) ss += __shfl_xor(ss, o);
    float inv = rsqrtf(ss * (1.0f / 128.0f) + 1e-6f);
    x0 *= inv * wn[l];
    x1 *= inv * wn[l + 64];
    float invf = exp2f(-(float)l * (13.287712379549449f / 64.0f));
    float ang  = (float)s * invf;
    float c, sn;
    sincosf(ang, &sn, &c);
    float y0 = (x0 * c - x1 * sn) * scale;
    float y1 = (x1 * c + x0 * sn) * scale;
    if (hh < NH) {
        p[l]      = (__bf16)y0;
        p[l + 64] = (__bf16)y1;
    } else {
        const int kh = hh - NH, key = s & 63;
        char* tile = (char*)Kt + (size_t)(kh * 32 + (s >> 6)) * 16384 + key * 256;
        const int sw = (key & 15) << 4;
        *reinterpret_cast<__bf16*>(tile + ((((l)      >> 3) << 4) ^ sw) + (l & 7) * 2) = (__bf16)y0;
        *reinterpret_cast<__bf16*>(tile + ((((l + 64) >> 3) << 4) ^ sw) + (l & 7) * 2) = (__bf16)y1;
    }
}

// ---- split-K MFMA flash attention, static-max softmax ------------------
// 8-wave blocks, 128 Q-rows, 128-kv-row staged unit. R5-verified; NEW:
// XCD-chunked swizzle so each XCD's blocks share one kh's K/V in its L2.
__global__ __launch_bounds__(512)
void attn_split(const __bf16* __restrict__ qkv,
                const __bf16* __restrict__ Kt, const __bf16* __restrict__ Vt,
                __bf16* __restrict__ Op, float* __restrict__ Lp)
{
    __shared__ char Ks[32768];
    __shared__ char Vs[32768];
    __shared__ char Ps[8][2048];

    int flat = blockIdx.x + 2 * (blockIdx.y + 16 * blockIdx.z);   // 512 blocks
    flat = (flat & 7) * 64 + (flat >> 3);
    const int c = flat & 1, qt = 15 - ((flat >> 1) & 15), h = flat >> 5;

    if (c * 8 > qt) return;
    const int kend = min(qt, c * 8 + 7);
    const int tid = threadIdx.x, lane = tid & 63, w = tid >> 6;
    const int mm = lane & 15, quad = lane >> 4;
    const int kh = h >> 2;

    bf8v aq[4];
    const __bf16* qbase = qkv + (size_t)(qt * 128 + w * 16 + mm) * QS + h * HD;
#pragma unroll
    for (int ks = 0; ks < 4; ++ks)
        aq[ks] = *reinterpret_cast<const bf8v*>(qbase + ks * 32 + quad * 8);

    float lp[4] = {};
    f4v oacc[8] = {};

    const char* kbase = (const char*)Kt + (size_t)(kh * 32) * 16384;
    const char* vbase = (const char*)Vt + (size_t)(kh * 32) * 16384;

    for (int tt = c * 8; tt <= kend; ++tt) {
        wgb();                                      // prev compute done (WAR)
#pragma unroll
        for (int j = 0; j < 4; ++j) {
            int chunk = w * 4 + j;                  // 32 chunks = 2 sub-tiles
            gld16(kbase + (size_t)tt * 32768 + chunk * 1024 + lane * 16,
                  Ks + chunk * 1024);
            gld16(vbase + (size_t)tt * 32768 + chunk * 1024 + lane * 16,
                  Vs + chunk * 1024);
        }
        VMC(0);
        wgb();

        const int nss = (tt == qt && w < 4) ? 1 : 2; // skip fully-masked sub
        for (int ss = 0; ss < nss; ++ss) {
            const char* Ksub = Ks + ss * 16384;
            const char* Vsub = Vs + ss * 16384;

            f4v s[4] = {};
#pragma unroll
            for (int ks = 0; ks < 4; ++ks)
#pragma unroll
                for (int c16 = 0; c16 < 4; ++c16) {
                    bf8v b = *reinterpret_cast<const bf8v*>(
                        Ksub + (c16 * 16 + mm) * 256 + (((ks * 4 + quad) ^ mm) << 4));
                    s[c16] = __builtin_amdgcn_mfma_f32_16x16x32_bf16(aq[ks], b, s[c16], 0, 0, 0);
                }
            if (tt == qt) {
#pragma unroll
                for (int c16 = 0; c16 < 4; ++c16)
#pragma unroll
                    for (int r = 0; r < 4; ++r)
                        if (ss * 64 + c16 * 16 + mm > w * 16 + quad * 4 + r)
                            s[c16][r] = -__builtin_inff();
            }
            float pr[4][4];
#pragma unroll
            for (int c16 = 0; c16 < 4; ++c16)
#pragma unroll
                for (int r = 0; r < 4; ++r) {
                    pr[c16][r] = __expf(s[c16][r]);
                    lp[r] += pr[c16][r];
                }
#pragma unroll
            for (int c16 = 0; c16 < 4; ++c16)
#pragma unroll
                for (int r = 0; r < 4; ++r) {
                    float mine  = pr[c16][r];
                    float other = __shfl_xor(mine, 1);
                    if ((mm & 1) == 0) {
                        int roww = quad * 4 + r;
                        int cc   = c16 * 2 + (mm >> 3);
                        *reinterpret_cast<bf2v*>(
                            &Ps[w][roww * 128 + ((cc ^ (roww & 7)) << 4) + (mm & 7) * 2]) =
                            bf2v{ (__bf16)mine, (__bf16)other };
                    }
                }
            bf8v pa[2];
#pragma unroll
            for (int kb = 0; kb < 2; ++kb)
                pa[kb] = *reinterpret_cast<const bf8v*>(
                    &Ps[w][mm * 128 + (((kb * 4 + quad) ^ (mm & 7)) << 4)]);
#pragma unroll
            for (int nb = 0; nb < 8; ++nb) {
                int d = nb * 16 + mm;
#pragma unroll
                for (int kb = 0; kb < 2; ++kb) {
                    bf8v bv = *reinterpret_cast<const bf8v*>(
                        Vsub + d * 128 + (((kb * 4 + quad) ^ (d & 7)) << 4));
                    oacc[nb] = __builtin_amdgcn_mfma_f32_16x16x32_bf16(pa[kb], bv, oacc[nb], 0, 0, 0);
                }
            }
        }
    }
#pragma unroll
    for (int off = 1; off < 16; off <<= 1)
#pragma unroll
        for (int r = 0; r < 4; ++r) lp[r] += __shfl_xor(lp[r], off);
#pragma unroll
    for (int r = 0; r < 4; ++r) {
        int row = qt * 128 + w * 16 + quad * 4 + r;
        size_t obase = ((size_t)(c * 16 + h) * SEQ + row) * HD;
#pragma unroll
        for (int nb = 0; nb < 8; ++nb)
            Op[obase + nb * 16 + mm] = (__bf16)oacc[nb][r];
        if (mm == 0)
            Lp[(size_t)(c * 16 + h) * SEQ + row] = lp[r];
    }
}

// ---- combine split-K partials -> ab (bf16 [row][h*128+d]) --------------
__global__ __launch_bounds__(256)
void combine(const __bf16* __restrict__ Op, const float* __restrict__ Lp,
             __bf16* __restrict__ ab)
{
    const int row = blockIdx.x, h = blockIdx.y * 4 + threadIdx.y, l = threadIdx.x;
    const int nch = (row >> 10) + 1;               // 1024 kv rows per chunk
    float L = 0.f, a0 = 0.f, a1 = 0.f;
    for (int c = 0; c < nch; ++c) {
        L += Lp[(size_t)(c * 16 + h) * SEQ + row];
        bf2v p = *reinterpret_cast<const bf2v*>(
            Op + ((size_t)(c * 16 + h) * SEQ + row) * HD + 2 * l);
        a0 += (float)p[0];
        a1 += (float)p[1];
    }
    float inv = 1.f / L;
    *reinterpret_cast<bf2v*>(ab + (size_t)row * (NH * HD) + h * HD + 2 * l) =
        bf2v{ (__bf16)(a0 * inv), (__bf16)(a1 * inv) };
}

extern "C" void kernel_launch(void* const* d_in, const int* in_sizes, int n_in,
                              void* d_out, int out_size, void* d_ws, size_t ws_size,
                              hipStream_t stream)
{
    const float* hs  = (const float*)d_in[0];
    const float* mu  = (const float*)d_in[1];
    const float* wq  = (const float*)d_in[2];
    const float* wk  = (const float*)d_in[3];
    const float* wv  = (const float*)d_in[4];
    const float* wo  = (const float*)d_in[5];
    const float* wmq = (const float*)d_in[6];
    const float* wmk = (const float*)d_in[7];
    const float* wmv = (const float*)d_in[8];
    const float* qw  = (const float*)d_in[9];
    const float* kw  = (const float*)d_in[10];
    float* out = (float*)d_out;

    char* ws = (char*)d_ws;
    // phase 1 (projection):
    __bf16* Wcat = (__bf16*)(ws + 0);          // [3072,4096] 25.2 MB
    __bf16* Acat = (__bf16*)(ws + 25165824);   // [2048,4096] 16.8 MB
    __bf16* Wo   = (__bf16*)(ws + 41943040);   // [2048,2048]  8.4 MB
    __bf16* qkvp = (__bf16*)(ws + 50331648);   // 2x[2048,3072] bf16 partials
    __bf16* ab   = (__bf16*)(ws + 75497472);   // [2048,2048] bf16, peak 83.9 MB
    // phase 2 aliases (Wcat/Acat dead after QKV GEMM):
    __bf16* Ktl  = (__bf16*)(ws + 0);          // 2 MB
    __bf16* Vtl  = (__bf16*)(ws + 2097152);    // 2 MB
    __bf16* Opart= (__bf16*)(ws + 4194304);    // 2x16 chunk-images = 16 MB
    float*  Lpart= (float*) (ws + 37748736);   // 0.25 MB

    // single fused convert pass
    cvt_all<<<dim3(24576), 256, 0, stream>>>(Acat, Wcat, Wo,
                                             hs, mu, wq, wmq, wk, wmk, wv, wmv, wo);

    // QKV projection: 256^2 pipelined, split-K=2 -> 192 blocks (bf16 partials)
    gemm_nt_pl<<<dim3(QS / 256, SEQ / 256, 2), 512, 0, stream>>>(
        Acat, Wcat, qkvp, SEQ, QS, 2 * HID_DIM, HID_DIM, nullptr, 0);
    // norm+rope; q in place, k packed into Ktl, v packed into Vtl (all fused)
    norm_rope_pk<<<dim3(SEQ, 6), dim3(64, 4), 0, stream>>>(
        qkvp, qkvp + (size_t)SEQ * QS, qw, kw, Ktl, Vtl);
    // attention: 8-wave blocks, 128 Q-rows, split-K chunk = 1024 kv rows
    attn_split<<<dim3(2, 16, NH), 512, 0, stream>>>(qkvp, Ktl, Vtl, Opart, Lpart);
    combine<<<dim3(SEQ, 4), dim3(64, 4), 0, stream>>>(Opart, Lpart, ab);
    // output projection: split-K=4 -> 256 blocks, fp32 atomic accumulate
    hipMemsetAsync(out, 0, (size_t)SEQ * HID_DIM * sizeof(float), stream);
    gemm_nt_pl<<<dim3(HID_DIM / 256, SEQ / 256, 4), 512, 0, stream>>>(
        ab, Wo, nullptr, SEQ, HID_DIM, NH * HD, 512, out, 1);
}

// Round 9
// 314.375 us; speedup vs baseline: 1.1222x; 1.1222x over previous
//
#include <hip/hip_runtime.h>
#include <math.h>

#define SEQ 2048
#define HID_DIM 2048
#define NH 16
#define NKV 4
#define HD 128
#define QS 3072   // fused qkv row stride (bf16): [q 2048 | k 512 | v 512]

typedef float  f4v  __attribute__((ext_vector_type(4)));
typedef __bf16 bf8v __attribute__((ext_vector_type(8)));
typedef __bf16 bf4v __attribute__((ext_vector_type(4)));
typedef __bf16 bf2v __attribute__((ext_vector_type(2)));

typedef __attribute__((address_space(1))) const void* gvp;
typedef __attribute__((address_space(3))) void*       svp;

__device__ __forceinline__ void gld16(const void* g, void* lds_wave_base) {
    __builtin_amdgcn_global_load_lds((gvp)g, (svp)lds_wave_base, 16, 0, 0);
}

__device__ __forceinline__ void wgb() {
    asm volatile("" ::: "memory");
    __builtin_amdgcn_s_barrier();
    asm volatile("" ::: "memory");
}
#define VMC(n) asm volatile("s_waitcnt vmcnt(" #n ")" ::: "memory")

// ---- single fused fp32 -> bf16 convert pass ----------------------------
__global__ __launch_bounds__(256)
void cvt_all(__bf16* __restrict__ Acat, __bf16* __restrict__ Wcat,
             __bf16* __restrict__ Wo,
             const float* __restrict__ hs, const float* __restrict__ mu,
             const float* __restrict__ wq, const float* __restrict__ wmq,
             const float* __restrict__ wk, const float* __restrict__ wmk,
             const float* __restrict__ wv, const float* __restrict__ wmv,
             const float* __restrict__ wo)
{
    int b = blockIdx.x;
    const float *s0, *s1; __bf16* dst;
    if (b < 8192)       { s0 = hs; s1 = mu;  dst = Acat; }
    else if (b < 16384) { s0 = wq; s1 = wmq; dst = Wcat;                            b -= 8192; }
    else if (b < 18432) { s0 = wk; s1 = wmk; dst = Wcat + (size_t)2048 * 4096;      b -= 16384; }
    else if (b < 20480) { s0 = wv; s1 = wmv; dst = Wcat + (size_t)2560 * 4096;      b -= 18432; }
    else {
        int i = (b - 20480) * 256 + threadIdx.x;
        float4 v = *reinterpret_cast<const float4*>(wo + (size_t)i * 4);
        *reinterpret_cast<bf4v*>(Wo + (size_t)i * 4) =
            bf4v{ (__bf16)v.x, (__bf16)v.y, (__bf16)v.z, (__bf16)v.w };
        return;
    }
    int i = b * 256 + threadIdx.x;
    int row = i >> 10, c = i & 1023;               // 1024 quads per dst row
    const float* s = (c < 512) ? s0 + ((size_t)row * 512 + c) * 4
                               : s1 + ((size_t)row * 512 + (c - 512)) * 4;
    float4 v = *reinterpret_cast<const float4*>(s);
    *reinterpret_cast<bf4v*>(dst + ((size_t)row * 1024 + c) * 4) =
        bf4v{ (__bf16)v.x, (__bf16)v.y, (__bf16)v.z, (__bf16)v.w };
}

// ---- 256x256 pipelined split-K NT GEMM, bf16 partials ------------------
// R5-verified schedule + XCD-chunked blockIdx swizzle (T1, bijective since
// nwg%8==0). bf16 partial output restored (R8's atomic epilogue cost the
// out-proj 25->70 us: 75 MB of RMW write traffic — reverted).
__device__ __forceinline__ void stage_half(
    const __bf16* __restrict__ g, int ldk, int row0, int ktile, int half,
    char* buf, int w, int sr, int sc)
{
#pragma unroll
    for (int j = 0; j < 2; ++j) {
        int sid = w * 2 + j;                       // 16 subtiles / half-tile
        int rb = half * 8 + (sid >> 1), cb = sid & 1;
        gld16(g + (size_t)(row0 + rb * 16 + sr) * ldk + ktile * 64 + cb * 32 + sc,
              buf + (rb * 2 + cb) * 1024);
    }
}
__device__ __forceinline__ void stage_tile(
    const __bf16* __restrict__ g, int ldk, int row0, int ktile,
    char* buf, int w, int sr, int sc)
{
    stage_half(g, ldk, row0, ktile, 0, buf, w, sr, sc);
    stage_half(g, ldk, row0, ktile, 1, buf, w, sr, sc);
}

#define LOAD_AF(DST, BUF, MTB) \
    _Pragma("unroll") for (int mt = 0; mt < 4; ++mt) \
    _Pragma("unroll") for (int ks = 0; ks < 2; ++ks) \
        DST[mt][ks] = *(const bf8v*)((BUF) + (((wm * 8 + (MTB) + mt) * 2 + ks) << 10) + frag_off);
#define LOAD_BF(DST, BUF, NTB) \
    _Pragma("unroll") for (int nt = 0; nt < 2; ++nt) \
    _Pragma("unroll") for (int ks = 0; ks < 2; ++ks) \
        DST[nt][ks] = *(const bf8v*)((BUF) + (((wn * 4 + (NTB) + nt) * 2 + ks) << 10) + frag_off);
#define MFMA_Q(MTB, NTB, AR, BR) \
    __builtin_amdgcn_s_setprio(1); \
    _Pragma("unroll") for (int mt = 0; mt < 4; ++mt) \
    _Pragma("unroll") for (int nt = 0; nt < 2; ++nt) \
    _Pragma("unroll") for (int ks = 0; ks < 2; ++ks) \
        acc[(MTB) + mt][(NTB) + nt] = __builtin_amdgcn_mfma_f32_16x16x32_bf16( \
            AR[mt][ks], BR[nt][ks], acc[(MTB) + mt][(NTB) + nt], 0, 0, 0); \
    __builtin_amdgcn_s_setprio(0);

__global__ __launch_bounds__(512, 2)
void gemm_nt_pl(const __bf16* __restrict__ A, const __bf16* __restrict__ B,
                __bf16* __restrict__ P, int M, int N, int K, int KS)
{
    __shared__ __align__(1024) char lds[131072];
    char* A0 = lds;
    char* A1 = lds + 32768;
    char* B0 = lds + 65536;
    char* B1 = lds + 98304;

    const int tid = threadIdx.x, lane = tid & 63, w = tid >> 6;
    const int wm = w >> 2, wn = w & 3;
    const int mm = lane & 15, quad = lane >> 4;

    // XCD-chunked swizzle (nwg % 8 == 0 for all launches here)
    const int nbx = gridDim.x, nby = gridDim.y;
    int flat = blockIdx.x + nbx * (blockIdx.y + nby * blockIdx.z);
    const int cpx = (nbx * nby * gridDim.z) >> 3;
    flat = (flat & 7) * cpx + (flat >> 3);
    const int bxi = flat % nbx, byi = (flat / nbx) % nby, bzi = flat / (nbx * nby);

    const int m0 = byi * 256, n0 = bxi * 256;
    const int kt0 = (bzi * KS) >> 6;
    const int T = KS >> 6;                          // K-tiles per block (>=4, even)

    const int sr = lane >> 2, sc = (lane & 3) * 8;  // staging lane offsets
    const int frag_off = (mm * 4 + quad) << 4;      // frag read offset in subtile

    f4v acc[8][4] = {};
    bf8v aLo[4][2], aHi[4][2], b01e[2][2], b01o[2][2], b23[2][2];

    // prologue: fully stage tiles kt0 (buf0), kt0+1 (buf1)
    stage_tile(A, K, m0, kt0,     A0, w, sr, sc);
    stage_tile(B, K, n0, kt0,     B0, w, sr, sc);
    stage_tile(A, K, m0, kt0 + 1, A1, w, sr, sc);
    stage_tile(B, K, n0, kt0 + 1, B1, w, sr, sc);
    VMC(8);                                         // drain tile kt0 (oldest 8)
    wgb();
    LOAD_AF(aLo, A0, 0)
    LOAD_BF(b01e, B0, 0)

    const int nbody = (T - 2) >> 1;
    for (int it = 0; it < nbody; ++it) {
        const int t2 = kt0 + 2 * it + 2, t3 = t2 + 1;
        // P1: rd b23(t); MFMA Q1(t)
        LOAD_BF(b23, B0, 2)
        MFMA_Q(0, 0, aLo, b01e)
        wgb();
        // P2: rd aHi(t); MFMA Q2(t); drain t+1
        LOAD_AF(aHi, A0, 4)
        MFMA_Q(0, 2, aLo, b23)
        VMC(0);
        wgb();
        // P3: rd aLo(t+1); stage B(t+2)->B0; MFMA Q3(t)
        LOAD_AF(aLo, A1, 0)
        stage_tile(B, K, n0, t2, B0, w, sr, sc);
        MFMA_Q(4, 2, aHi, b23)
        wgb();
        // P4: rd b01(t+1); stage A(t+2)->A0; MFMA Q4(t)
        LOAD_BF(b01o, B1, 0)
        stage_tile(A, K, m0, t2, A0, w, sr, sc);
        MFMA_Q(4, 0, aHi, b01e)
        wgb();
        // P5: rd b23(t+1); MFMA Q1(t+1)
        LOAD_BF(b23, B1, 2)
        MFMA_Q(0, 0, aLo, b01o)
        wgb();
        // P6: rd aHi(t+1); MFMA Q2(t+1); drain t+2
        LOAD_AF(aHi, A1, 4)
        MFMA_Q(0, 2, aLo, b23)
        VMC(0);
        wgb();
        // P7: rd aLo(t+2); stage B(t+3)->B1; MFMA Q3(t+1)
        LOAD_AF(aLo, A0, 0)
        stage_tile(B, K, n0, t3, B1, w, sr, sc);
        MFMA_Q(4, 2, aHi, b23)
        wgb();
        // P8: rd b01(t+2); stage A(t+3)->A1; MFMA Q4(t+1)
        LOAD_BF(b01e, B0, 0)
        stage_tile(A, K, m0, t3, A1, w, sr, sc);
        MFMA_Q(4, 0, aHi, b01o)
        wgb();
    }
    // tail: tiles T-2 (buf0), T-1 (buf1); no staging
    LOAD_BF(b23, B0, 2)
    MFMA_Q(0, 0, aLo, b01e)
    wgb();
    LOAD_AF(aHi, A0, 4)
    MFMA_Q(0, 2, aLo, b23)
    VMC(0);
    wgb();
    LOAD_AF(aLo, A1, 0)
    MFMA_Q(4, 2, aHi, b23)
    wgb();
    LOAD_BF(b01o, B1, 0)
    MFMA_Q(4, 0, aHi, b01e)
    wgb();
    LOAD_BF(b23, B1, 2)
    MFMA_Q(0, 0, aLo, b01o)
    wgb();
    LOAD_AF(aHi, A1, 4)
    MFMA_Q(0, 2, aLo, b23)
    wgb();
    MFMA_Q(4, 2, aHi, b23)
    MFMA_Q(4, 0, aHi, b01o)

    __bf16* Pz = P + (size_t)bzi * M * N;
#pragma unroll
    for (int mt = 0; mt < 8; ++mt)
#pragma unroll
        for (int nt = 0; nt < 4; ++nt)
#pragma unroll
            for (int r = 0; r < 4; ++r)
                Pz[(size_t)(m0 + wm * 128 + mt * 16 + quad * 4 + r) * N
                   + n0 + wn * 64 + nt * 16 + mm] = (__bf16)acc[mt][nt][r];
}

// ---- sum 4 bf16 partials -> fp32 out -----------------------------------
__global__ __launch_bounds__(256)
void add4(const __bf16* __restrict__ P, float* __restrict__ out, int n4)
{
    int i = blockIdx.x * 256 + threadIdx.x;
    if (i >= n4) return;
    float4 s = {0.f, 0.f, 0.f, 0.f};
#pragma unroll
    for (int z = 0; z < 4; ++z) {
        bf4v v = *reinterpret_cast<const bf4v*>(P + (size_t)z * n4 * 4 + (size_t)i * 4);
        s.x += (float)v[0]; s.y += (float)v[1]; s.z += (float)v[2]; s.w += (float)v[3];
    }
    *reinterpret_cast<float4*>(out + (size_t)i * 4) = s;
}

// ---- norm_rope fused with K-pack AND V-pack ----------------------------
// q-heads (hh<16): RMSNorm+RoPE in place. k-heads (16..19): normed+roped
// rows written straight into the packed XOR-swizzled Kt image. v-heads
// (20..23): partial-sum only, written transposed into the Vt image.
__global__ __launch_bounds__(256)
void norm_rope_pk(__bf16* __restrict__ qkv /* p0, q in place */,
                  const __bf16* __restrict__ p1,
                  const float* __restrict__ qw, const float* __restrict__ kw,
                  __bf16* __restrict__ Kt, __bf16* __restrict__ Vt)
{
    const int s = blockIdx.x, hh = blockIdx.y * 4 + threadIdx.y, l = threadIdx.x;
    if (hh >= NH + NKV) {                          // ---- V path ----
        const int vh = hh - (NH + NKV);
        const int off = 2560 + vh * HD;
        const __bf16* p  = qkv + (size_t)s * QS + off;
        const __bf16* q1 = p1  + (size_t)s * QS + off;
        float x0 = (float)p[l]      + (float)q1[l];
        float x1 = (float)p[l + 64] + (float)q1[l + 64];
        char* tile = (char*)Vt + (size_t)(vh * 32 + (s >> 6)) * 16384;
        const int kc = (s >> 3) & 7, j = s & 7;
        const int d2 = l + 64;
        *reinterpret_cast<__bf16*>(tile + l  * 128 + ((kc ^ (l  & 7)) << 4) + j * 2) = (__bf16)x0;
        *reinterpret_cast<__bf16*>(tile + d2 * 128 + ((kc ^ (d2 & 7)) << 4) + j * 2) = (__bf16)x1;
        return;
    }
    const float* wn; float scale; int off;
    if (hh < NH) { off = hh * HD;               wn = qw; scale = 0.08838834764831845f; }
    else         { off = 2048 + (hh - NH) * HD; wn = kw; scale = 1.0f; }
    __bf16* p = qkv + (size_t)s * QS + off;
    const __bf16* q1 = p1 + (size_t)s * QS + off;
    float x0 = (float)p[l]      + (float)q1[l];
    float x1 = (float)p[l + 64] + (float)q1[l + 64];
    float ss = x0 * x0 + x1 * x1;
#pragma unroll
    for (int o = 32; o; o >>= 1) ss += __shfl_xor(ss, o);
    float inv = rsqrtf(ss * (1.0f / 128.0f) + 1e-6f);
    x0 *= inv * wn[l];
    x1 *= inv * wn[l + 64];
    float invf = exp2f(-(float)l * (13.287712379549449f / 64.0f));
    float ang  = (float)s * invf;
    float c, sn;
    sincosf(ang, &sn, &c);
    float y0 = (x0 * c - x1 * sn) * scale;
    float y1 = (x1 * c + x0 * sn) * scale;
    if (hh < NH) {
        p[l]      = (__bf16)y0;
        p[l + 64] = (__bf16)y1;
    } else {
        const int kh = hh - NH, key = s & 63;
        char* tile = (char*)Kt + (size_t)(kh * 32 + (s >> 6)) * 16384 + key * 256;
        const int sw = (key & 15) << 4;
        *reinterpret_cast<__bf16*>(tile + ((((l)      >> 3) << 4) ^ sw) + (l & 7) * 2) = (__bf16)y0;
        *reinterpret_cast<__bf16*>(tile + ((((l + 64) >> 3) << 4) ^ sw) + (l & 7) * 2) = (__bf16)y1;
    }
}

// ---- split-K MFMA flash attention, static-max softmax ------------------
// 8-wave blocks, 128 Q-rows, 128-kv-row staged unit, XCD-chunked swizzle.
__global__ __launch_bounds__(512)
void attn_split(const __bf16* __restrict__ qkv,
                const __bf16* __restrict__ Kt, const __bf16* __restrict__ Vt,
                __bf16* __restrict__ Op, float* __restrict__ Lp)
{
    __shared__ char Ks[32768];
    __shared__ char Vs[32768];
    __shared__ char Ps[8][2048];

    int flat = blockIdx.x + 2 * (blockIdx.y + 16 * blockIdx.z);   // 512 blocks
    flat = (flat & 7) * 64 + (flat >> 3);
    const int c = flat & 1, qt = 15 - ((flat >> 1) & 15), h = flat >> 5;

    if (c * 8 > qt) return;
    const int kend = min(qt, c * 8 + 7);
    const int tid = threadIdx.x, lane = tid & 63, w = tid >> 6;
    const int mm = lane & 15, quad = lane >> 4;
    const int kh = h >> 2;

    bf8v aq[4];
    const __bf16* qbase = qkv + (size_t)(qt * 128 + w * 16 + mm) * QS + h * HD;
#pragma unroll
    for (int ks = 0; ks < 4; ++ks)
        aq[ks] = *reinterpret_cast<const bf8v*>(qbase + ks * 32 + quad * 8);

    float lp[4] = {};
    f4v oacc[8] = {};

    const char* kbase = (const char*)Kt + (size_t)(kh * 32) * 16384;
    const char* vbase = (const char*)Vt + (size_t)(kh * 32) * 16384;

    for (int tt = c * 8; tt <= kend; ++tt) {
        wgb();                                      // prev compute done (WAR)
#pragma unroll
        for (int j = 0; j < 4; ++j) {
            int chunk = w * 4 + j;                  // 32 chunks = 2 sub-tiles
            gld16(kbase + (size_t)tt * 32768 + chunk * 1024 + lane * 16,
                  Ks + chunk * 1024);
            gld16(vbase + (size_t)tt * 32768 + chunk * 1024 + lane * 16,
                  Vs + chunk * 1024);
        }
        VMC(0);
        wgb();

        const int nss = (tt == qt && w < 4) ? 1 : 2; // skip fully-masked sub
        for (int ss = 0; ss < nss; ++ss) {
            const char* Ksub = Ks + ss * 16384;
            const char* Vsub = Vs + ss * 16384;

            f4v s[4] = {};
#pragma unroll
            for (int ks = 0; ks < 4; ++ks)
#pragma unroll
                for (int c16 = 0; c16 < 4; ++c16) {
                    bf8v b = *reinterpret_cast<const bf8v*>(
                        Ksub + (c16 * 16 + mm) * 256 + (((ks * 4 + quad) ^ mm) << 4));
                    s[c16] = __builtin_amdgcn_mfma_f32_16x16x32_bf16(aq[ks], b, s[c16], 0, 0, 0);
                }
            if (tt == qt) {
#pragma unroll
                for (int c16 = 0; c16 < 4; ++c16)
#pragma unroll
                    for (int r = 0; r < 4; ++r)
                        if (ss * 64 + c16 * 16 + mm > w * 16 + quad * 4 + r)
                            s[c16][r] = -__builtin_inff();
            }
            float pr[4][4];
#pragma unroll
            for (int c16 = 0; c16 < 4; ++c16)
#pragma unroll
                for (int r = 0; r < 4; ++r) {
                    pr[c16][r] = __expf(s[c16][r]);
                    lp[r] += pr[c16][r];
                }
#pragma unroll
            for (int c16 = 0; c16 < 4; ++c16)
#pragma unroll
                for (int r = 0; r < 4; ++r) {
                    float mine  = pr[c16][r];
                    float other = __shfl_xor(mine, 1);
                    if ((mm & 1) == 0) {
                        int roww = quad * 4 + r;
                        int cc   = c16 * 2 + (mm >> 3);
                        *reinterpret_cast<bf2v*>(
                            &Ps[w][roww * 128 + ((cc ^ (roww & 7)) << 4) + (mm & 7) * 2]) =
                            bf2v{ (__bf16)mine, (__bf16)other };
                    }
                }
            bf8v pa[2];
#pragma unroll
            for (int kb = 0; kb < 2; ++kb)
                pa[kb] = *reinterpret_cast<const bf8v*>(
                    &Ps[w][mm * 128 + (((kb * 4 + quad) ^ (mm & 7)) << 4)]);
#pragma unroll
            for (int nb = 0; nb < 8; ++nb) {
                int d = nb * 16 + mm;
#pragma unroll
                for (int kb = 0; kb < 2; ++kb) {
                    bf8v bv = *reinterpret_cast<const bf8v*>(
                        Vsub + d * 128 + (((kb * 4 + quad) ^ (d & 7)) << 4));
                    oacc[nb] = __builtin_amdgcn_mfma_f32_16x16x32_bf16(pa[kb], bv, oacc[nb], 0, 0, 0);
                }
            }
        }
    }
#pragma unroll
    for (int off = 1; off < 16; off <<= 1)
#pragma unroll
        for (int r = 0; r < 4; ++r) lp[r] += __shfl_xor(lp[r], off);
#pragma unroll
    for (int r = 0; r < 4; ++r) {
        int row = qt * 128 + w * 16 + quad * 4 + r;
        size_t obase = ((size_t)(c * 16 + h) * SEQ + row) * HD;
#pragma unroll
        for (int nb = 0; nb < 8; ++nb)
            Op[obase + nb * 16 + mm] = (__bf16)oacc[nb][r];
        if (mm == 0)
            Lp[(size_t)(c * 16 + h) * SEQ + row] = lp[r];
    }
}

// ---- combine split-K partials -> ab (bf16 [row][h*128+d]) --------------
__global__ __launch_bounds__(256)
void combine(const __bf16* __restrict__ Op, const float* __restrict__ Lp,
             __bf16* __restrict__ ab)
{
    const int row = blockIdx.x, h = blockIdx.y * 4 + threadIdx.y, l = threadIdx.x;
    const int nch = (row >> 10) + 1;               // 1024 kv rows per chunk
    float L = 0.f, a0 = 0.f, a1 = 0.f;
    for (int c = 0; c < nch; ++c) {
        L += Lp[(size_t)(c * 16 + h) * SEQ + row];
        bf2v p = *reinterpret_cast<const bf2v*>(
            Op + ((size_t)(c * 16 + h) * SEQ + row) * HD + 2 * l);
        a0 += (float)p[0];
        a1 += (float)p[1];
    }
    float inv = 1.f / L;
    *reinterpret_cast<bf2v*>(ab + (size_t)row * (NH * HD) + h * HD + 2 * l) =
        bf2v{ (__bf16)(a0 * inv), (__bf16)(a1 * inv) };
}

extern "C" void kernel_launch(void* const* d_in, const int* in_sizes, int n_in,
                              void* d_out, int out_size, void* d_ws, size_t ws_size,
                              hipStream_t stream)
{
    const float* hs  = (const float*)d_in[0];
    const float* mu  = (const float*)d_in[1];
    const float* wq  = (const float*)d_in[2];
    const float* wk  = (const float*)d_in[3];
    const float* wv  = (const float*)d_in[4];
    const float* wo  = (const float*)d_in[5];
    const float* wmq = (const float*)d_in[6];
    const float* wmk = (const float*)d_in[7];
    const float* wmv = (const float*)d_in[8];
    const float* qw  = (const float*)d_in[9];
    const float* kw  = (const float*)d_in[10];
    float* out = (float*)d_out;

    char* ws = (char*)d_ws;
    // phase 1 (projection):
    __bf16* Wcat = (__bf16*)(ws + 0);          // [3072,4096] 25.2 MB
    __bf16* Acat = (__bf16*)(ws + 25165824);   // [2048,4096] 16.8 MB
    __bf16* Wo   = (__bf16*)(ws + 41943040);   // [2048,2048]  8.4 MB
    __bf16* qkvp = (__bf16*)(ws + 50331648);   // 2x[2048,3072] bf16 partials
    __bf16* ab   = (__bf16*)(ws + 75497472);   // [2048,2048] bf16, peak 83.9 MB
    // phase 2 aliases (Wcat/Acat dead after QKV GEMM):
    __bf16* Ktl  = (__bf16*)(ws + 0);          // 2 MB
    __bf16* Vtl  = (__bf16*)(ws + 2097152);    // 2 MB
    __bf16* Opart= (__bf16*)(ws + 4194304);    // 2x16 chunk-images = 16 MB
    float*  Lpart= (float*) (ws + 37748736);   // 0.25 MB
    // phase 3 alias (attn scratch dead after combine):
    __bf16* outp = (__bf16*)(ws + 0);          // 4x[2048,2048] bf16 = 33.6 MB

    // single fused convert pass
    cvt_all<<<dim3(24576), 256, 0, stream>>>(Acat, Wcat, Wo,
                                             hs, mu, wq, wmq, wk, wmk, wv, wmv, wo);

    // QKV projection: 256^2 pipelined, split-K=2 -> 192 blocks (bf16 partials)
    gemm_nt_pl<<<dim3(QS / 256, SEQ / 256, 2), 512, 0, stream>>>(
        Acat, Wcat, qkvp, SEQ, QS, 2 * HID_DIM, HID_DIM);
    // norm+rope; q in place, k packed into Ktl, v packed into Vtl (all fused)
    norm_rope_pk<<<dim3(SEQ, 6), dim3(64, 4), 0, stream>>>(
        qkvp, qkvp + (size_t)SEQ * QS, qw, kw, Ktl, Vtl);
    // attention: 8-wave blocks, 128 Q-rows, split-K chunk = 1024 kv rows
    attn_split<<<dim3(2, 16, NH), 512, 0, stream>>>(qkvp, Ktl, Vtl, Opart, Lpart);
    combine<<<dim3(SEQ, 4), dim3(64, 4), 0, stream>>>(Opart, Lpart, ab);
    // output projection: split-K=4 -> 256 blocks, bf16 partials + add pass
    gemm_nt_pl<<<dim3(HID_DIM / 256, SEQ / 256, 4), 512, 0, stream>>>(
        ab, Wo, outp, SEQ, HID_DIM, NH * HD, 512);
    add4<<<dim3((1024 * 1024 + 255) / 256), 256, 0, stream>>>(outp, out, 1024 * 1024);
}